// Round 7
// baseline (294.894 us; speedup 1.0000x reference)
//
#include <hip/hip_runtime.h>
#include <math.h>

#define N_NODES 100000
#define N_EDGES 1600000
#define F_IN 128
#define H_DIM 128
#define C_OUT 40
#define BN_EPS 1e-5f

#define ELL_W 64           // slots per node; Poisson(16) => P(deg>63) ~ 1e-17
#define CNT_STRIDE 16      // one counter per 64B line (kills cross-XCD line ping-pong)

#define G1_ROWS 128
#define G1_LD 136          // shorts: 272 B row
#define G1_NB ((N_NODES + G1_ROWS - 1) / G1_ROWS)       // 782
#define PS_LD 800          // pstats stride (>= G1_NB)

typedef unsigned short u16;
typedef unsigned int u32;
typedef __attribute__((ext_vector_type(8))) __bf16 bf16x8;
typedef __attribute__((ext_vector_type(4))) float f32x4;

__device__ __forceinline__ u16 f2bf(float f) {              // RNE
    u32 u = __float_as_uint(f);
    u += 0x7FFFu + ((u >> 16) & 1u);
    return (u16)(u >> 16);
}
__device__ __forceinline__ float bf2f(u16 h) {
    return __uint_as_float(((u32)h) << 16);
}
// packed dword of 2 bf16 -> two f32 adds (2 VALU each)
__device__ __forceinline__ void add2(float* a0, float* a1, u32 d) {
    *a0 += __uint_as_float(d << 16);
    *a1 += __uint_as_float(d & 0xFFFF0000u);
}

// ---------------- ELL build (no scan, no separate fill pass) ----------------
__global__ __launch_bounds__(256) void ell_init(int* __restrict__ cnt_pad,
                                                int* __restrict__ ell) {
    int i = blockIdx.x * 256 + threadIdx.x;
    if (i < N_NODES) {
        cnt_pad[i * CNT_STRIDE] = 1;        // self-loop occupies slot 0
        ell[i * ELL_W] = i;
    }
}

__global__ __launch_bounds__(256) void ell_fill(const int* __restrict__ src,
                                                const int* __restrict__ dst,
                                                int* __restrict__ cnt_pad,
                                                int* __restrict__ ell) {
    int e = blockIdx.x * 256 + threadIdx.x;
    if (e < N_EDGES) {
        int d = dst[e];
        int ret = atomicAdd(&cnt_pad[d * CNT_STRIDE], 1);
        if (ret < ELL_W) ell[d * ELL_W + ret] = src[e];   // guard: never triggers
    }
}

__global__ __launch_bounds__(256) void dinv_k(const int* __restrict__ cnt_pad,
                                              float* __restrict__ dinv) {
    int i = blockIdx.x * 256 + threadIdx.x;
    if (i < N_NODES) dinv[i] = rsqrtf((float)cnt_pad[i * CNT_STRIDE]);
}

// ---------------- xs = dinv[n] * x (bf16, RNE) ----------------
__global__ __launch_bounds__(256) void xconvert(const float* __restrict__ x,
                                                const float* __restrict__ dinv,
                                                u16* __restrict__ xs) {
    int i = blockIdx.x * 256 + threadIdx.x;      // exactly 3.2M threads (float4 units)
    int n = i >> 5;                              // 32 float4 per row
    float dd = dinv[n];
    float4 v = ((const float4*)x)[i];
    ushort4 o;
    o.x = f2bf(v.x * dd); o.y = f2bf(v.y * dd);
    o.z = f2bf(v.z * dd); o.w = f2bf(v.w * dd);
    ((ushort4*)xs)[i] = o;
}

// W1 [k][n] f32 -> W1t [n][k] bf16
__global__ __launch_bounds__(256) void wconvert(const float* __restrict__ W1,
                                                u16* __restrict__ W1t) {
    int i = blockIdx.x * 256 + threadIdx.x;      // 16384
    int k = i >> 7, n = i & 127;
    W1t[n * H_DIM + k] = f2bf(W1[k * H_DIM + n]);
}

// ------- gather layer 1: aggb[n] = bf16( dinv[n] * sum_{s in N(n)} xs[s] ) --
// 16 lanes/node (8 ch each, int4), 16 nodes/block, 4-edge unroll.
__global__ __launch_bounds__(256) void gather_x(const int* __restrict__ cnt_pad,
                                                const int* __restrict__ ell,
                                                const float* __restrict__ dinv,
                                                const u16* __restrict__ xs,
                                                u16* __restrict__ aggb) {
    int node = blockIdx.x * 16 + (threadIdx.x >> 4);     // grid exact: N%16==0
    int q = threadIdx.x & 15;
    int len = cnt_pad[node * CNT_STRIDE];
    if (len > ELL_W) len = ELL_W;
    const int* row = ell + node * ELL_W;
    float acc[8] = {};
    int e = 0;
    for (; e + 3 < len; e += 4) {
        int s0 = row[e], s1 = row[e + 1], s2 = row[e + 2], s3 = row[e + 3];
        int4 v0 = *(const int4*)(xs + (size_t)s0 * F_IN + q * 8);
        int4 v1 = *(const int4*)(xs + (size_t)s1 * F_IN + q * 8);
        int4 v2 = *(const int4*)(xs + (size_t)s2 * F_IN + q * 8);
        int4 v3 = *(const int4*)(xs + (size_t)s3 * F_IN + q * 8);
        add2(&acc[0], &acc[1], (u32)v0.x); add2(&acc[2], &acc[3], (u32)v0.y);
        add2(&acc[4], &acc[5], (u32)v0.z); add2(&acc[6], &acc[7], (u32)v0.w);
        add2(&acc[0], &acc[1], (u32)v1.x); add2(&acc[2], &acc[3], (u32)v1.y);
        add2(&acc[4], &acc[5], (u32)v1.z); add2(&acc[6], &acc[7], (u32)v1.w);
        add2(&acc[0], &acc[1], (u32)v2.x); add2(&acc[2], &acc[3], (u32)v2.y);
        add2(&acc[4], &acc[5], (u32)v2.z); add2(&acc[6], &acc[7], (u32)v2.w);
        add2(&acc[0], &acc[1], (u32)v3.x); add2(&acc[2], &acc[3], (u32)v3.y);
        add2(&acc[4], &acc[5], (u32)v3.z); add2(&acc[6], &acc[7], (u32)v3.w);
    }
    for (; e < len; ++e) {
        int s = row[e];
        int4 v = *(const int4*)(xs + (size_t)s * F_IN + q * 8);
        add2(&acc[0], &acc[1], (u32)v.x); add2(&acc[2], &acc[3], (u32)v.y);
        add2(&acc[4], &acc[5], (u32)v.z); add2(&acc[6], &acc[7], (u32)v.w);
    }
    float dd = dinv[node];
    int4 o;
    o.x = (int)((u32)f2bf(acc[0] * dd) | ((u32)f2bf(acc[1] * dd) << 16));
    o.y = (int)((u32)f2bf(acc[2] * dd) | ((u32)f2bf(acc[3] * dd) << 16));
    o.z = (int)((u32)f2bf(acc[4] * dd) | ((u32)f2bf(acc[5] * dd) << 16));
    o.w = (int)((u32)f2bf(acc[6] * dd) | ((u32)f2bf(acc[7] * dd) << 16));
    *(int4*)(aggb + (size_t)node * H_DIM + q * 8) = o;
}

// ------------- GEMM1 via MFMA: hb = relu(aggb@W1 + b1) (bf16) --------------
// BN partial stats -> pstats[c][blk], plain stores.
__global__ __launch_bounds__(256) void gemm1_mfma(const u16* __restrict__ aggb,
                                                  const u16* __restrict__ W1t,
                                                  const float* __restrict__ b1,
                                                  u16* __restrict__ hb,
                                                  float* __restrict__ pstats) {
    __shared__ u16 As[G1_ROWS * G1_LD];   // 34.8 KB
    int tid = threadIdx.x;
    int base = blockIdx.x * G1_ROWS;

    {   // stage 128 node rows (256 B each), clamped at tail
        int row = tid >> 1, half = tid & 1;
        int gr = base + row; if (gr >= N_NODES) gr = N_NODES - 1;
        const int4* gsrc = (const int4*)(aggb + (size_t)gr * H_DIM + half * 64);
        int4* ldst = (int4*)(As + row * G1_LD + half * 64);
        #pragma unroll
        for (int i = 0; i < 8; ++i) ldst[i] = gsrc[i];
    }
    __syncthreads();

    int lane = tid & 63, w = tid >> 6;
    int r = lane & 15, g = lane >> 4;

    bf16x8 wf[2][4];   // [ch-tile][kstep], resident
    #pragma unroll
    for (int t = 0; t < 2; ++t)
        #pragma unroll
        for (int ks = 0; ks < 4; ++ks)
            wf[t][ks] = *(const bf16x8*)(W1t + (w * 32 + t * 16 + r) * H_DIM + ks * 32 + g * 8);

    float bch[2][4];
    #pragma unroll
    for (int t = 0; t < 2; ++t)
        #pragma unroll
        for (int i = 0; i < 4; ++i)
            bch[t][i] = b1[w * 32 + t * 16 + 4 * g + i];

    float cs[8] = {}, cq[8] = {};

    for (int rt = 0; rt < 8; ++rt) {
        f32x4 acc0 = {0.f, 0.f, 0.f, 0.f}, acc1 = {0.f, 0.f, 0.f, 0.f};
        #pragma unroll
        for (int ks = 0; ks < 4; ++ks) {
            bf16x8 nf = *(const bf16x8*)(As + (rt * 16 + r) * G1_LD + ks * 32 + g * 8);
            acc0 = __builtin_amdgcn_mfma_f32_16x16x32_bf16(wf[0][ks], nf, acc0, 0, 0, 0);
            acc1 = __builtin_amdgcn_mfma_f32_16x16x32_bf16(wf[1][ks], nf, acc1, 0, 0, 0);
        }
        int node = base + rt * 16 + r;
        if (node < N_NODES) {
            float o0[4], o1[4];
            #pragma unroll
            for (int i = 0; i < 4; ++i) {
                o0[i] = fmaxf(acc0[i] + bch[0][i], 0.f);
                o1[i] = fmaxf(acc1[i] + bch[1][i], 0.f);
                cs[i]     += o0[i]; cq[i]     += o0[i] * o0[i];
                cs[4 + i] += o1[i]; cq[4 + i] += o1[i] * o1[i];
            }
            uint2 p0, p1;
            p0.x = (u32)f2bf(o0[0]) | ((u32)f2bf(o0[1]) << 16);
            p0.y = (u32)f2bf(o0[2]) | ((u32)f2bf(o0[3]) << 16);
            p1.x = (u32)f2bf(o1[0]) | ((u32)f2bf(o1[1]) << 16);
            p1.y = (u32)f2bf(o1[2]) | ((u32)f2bf(o1[3]) << 16);
            u16* hp = hb + (size_t)node * H_DIM + w * 32 + 4 * g;
            *(uint2*)hp = p0;
            *(uint2*)(hp + 16) = p1;
        }
    }

    #pragma unroll
    for (int j = 0; j < 8; ++j) {
        #pragma unroll
        for (int m = 1; m < 16; m <<= 1) {
            cs[j] += __shfl_xor(cs[j], m, 16);
            cq[j] += __shfl_xor(cq[j], m, 16);
        }
    }
    if (r == 0) {
        #pragma unroll
        for (int j = 0; j < 8; ++j) {
            int c = w * 32 + (j >> 2) * 16 + 4 * g + (j & 3);
            pstats[c * PS_LD + blockIdx.x] = cs[j];
            pstats[(128 + c) * PS_LD + blockIdx.x] = cq[j];
        }
    }
}

// ---- reduce per-block partials -> scale/shift (one block per channel) ----
__global__ __launch_bounds__(256) void stats_final(const float* __restrict__ pstats,
                                                   const float* __restrict__ gamma,
                                                   const float* __restrict__ beta,
                                                   float* __restrict__ scale,
                                                   float* __restrict__ shift) {
    __shared__ float ls[256], lq[256];
    int c = blockIdx.x, t = threadIdx.x;
    float s = 0.f, q = 0.f;
    for (int b = t; b < G1_NB; b += 256) {
        s += pstats[c * PS_LD + b];
        q += pstats[(128 + c) * PS_LD + b];
    }
    ls[t] = s; lq[t] = q;
    __syncthreads();
    for (int off = 128; off; off >>= 1) {
        if (t < off) { ls[t] += ls[t + off]; lq[t] += lq[t + off]; }
        __syncthreads();
    }
    if (t == 0) {
        const float invn = 1.0f / (float)N_NODES;
        float mean = ls[0] * invn;
        float var = lq[0] * invn - mean * mean;
        float sc = gamma[c] * rsqrtf(var + BN_EPS);
        scale[c] = sc;
        shift[c] = beta[c] - mean * sc;
    }
}

// ---- fold BN into layer-2 weights: W2t[c][k] = bf16(scale[k]*W2[k][c]),
// padded to 48 channels; K[c] = sum_k shift[k]*W2[k][c] (f32, 48 entries) ----
__global__ __launch_bounds__(256) void w2fold(const float* __restrict__ W2,
                                              const float* __restrict__ scale,
                                              const float* __restrict__ shift,
                                              u16* __restrict__ W2t,
                                              float* __restrict__ K) {
    int t = threadIdx.x;
    for (int i = t; i < 48 * 128; i += 256) {
        int c = i >> 7, k = i & 127;
        W2t[i] = (c < C_OUT) ? f2bf(scale[k] * W2[k * C_OUT + c]) : (u16)0;
    }
    if (t < 48) {
        float a = 0.f;
        if (t < C_OUT)
            for (int k = 0; k < H_DIM; ++k) a += shift[k] * W2[k * C_OUT + t];
        K[t] = a;
    }
}

// ---- GEMM2 via MFMA: h2s[n] = bf16( dinv[n] * (hb[n]@W2t + K) )  (48 ch) ---
__global__ __launch_bounds__(256) void gemm2_mfma(const u16* __restrict__ hb,
                                                  const u16* __restrict__ W2t,
                                                  const float* __restrict__ K,
                                                  const float* __restrict__ dinv,
                                                  u16* __restrict__ h2s) {
    __shared__ u16 As[G1_ROWS * G1_LD];
    int tid = threadIdx.x;
    int base = blockIdx.x * G1_ROWS;

    {
        int row = tid >> 1, half = tid & 1;
        int gr = base + row; if (gr >= N_NODES) gr = N_NODES - 1;
        const int4* gsrc = (const int4*)(hb + (size_t)gr * H_DIM + half * 64);
        int4* ldst = (int4*)(As + row * G1_LD + half * 64);
        #pragma unroll
        for (int i = 0; i < 8; ++i) ldst[i] = gsrc[i];
    }
    __syncthreads();

    int lane = tid & 63, w = tid >> 6;
    int r = lane & 15, g = lane >> 4;

    bf16x8 wf[3][4];
    #pragma unroll
    for (int t = 0; t < 3; ++t)
        #pragma unroll
        for (int ks = 0; ks < 4; ++ks)
            wf[t][ks] = *(const bf16x8*)(W2t + (t * 16 + r) * H_DIM + ks * 32 + g * 8);

    float kv[3][4];
    #pragma unroll
    for (int t = 0; t < 3; ++t)
        #pragma unroll
        for (int i = 0; i < 4; ++i)
            kv[t][i] = K[t * 16 + 4 * g + i];

    f32x4 acc[2][3];
    #pragma unroll
    for (int i2 = 0; i2 < 2; ++i2)
        #pragma unroll
        for (int t = 0; t < 3; ++t)
            acc[i2][t] = (f32x4){0.f, 0.f, 0.f, 0.f};

    #pragma unroll
    for (int i2 = 0; i2 < 2; ++i2) {
        int rt = 2 * w + i2;
        #pragma unroll
        for (int ks = 0; ks < 4; ++ks) {
            bf16x8 nf = *(const bf16x8*)(As + (rt * 16 + r) * G1_LD + ks * 32 + g * 8);
            acc[i2][0] = __builtin_amdgcn_mfma_f32_16x16x32_bf16(wf[0][ks], nf, acc[i2][0], 0, 0, 0);
            acc[i2][1] = __builtin_amdgcn_mfma_f32_16x16x32_bf16(wf[1][ks], nf, acc[i2][1], 0, 0, 0);
            acc[i2][2] = __builtin_amdgcn_mfma_f32_16x16x32_bf16(wf[2][ks], nf, acc[i2][2], 0, 0, 0);
        }
    }

    #pragma unroll
    for (int i2 = 0; i2 < 2; ++i2) {
        int node = base + (2 * w + i2) * 16 + r;
        if (node < N_NODES) {
            float dd = dinv[node];
            u16* hp = h2s + (size_t)node * C_OUT + 4 * g;
            #pragma unroll
            for (int t = 0; t < 2; ++t) {
                uint2 p;
                p.x = (u32)f2bf((acc[i2][t][0] + kv[t][0]) * dd) |
                      ((u32)f2bf((acc[i2][t][1] + kv[t][1]) * dd) << 16);
                p.y = (u32)f2bf((acc[i2][t][2] + kv[t][2]) * dd) |
                      ((u32)f2bf((acc[i2][t][3] + kv[t][3]) * dd) << 16);
                *(uint2*)(hp + t * 16) = p;
            }
            if (g < 2) {
                uint2 p;
                p.x = (u32)f2bf((acc[i2][2][0] + kv[2][0]) * dd) |
                      ((u32)f2bf((acc[i2][2][1] + kv[2][1]) * dd) << 16);
                p.y = (u32)f2bf((acc[i2][2][2] + kv[2][2]) * dd) |
                      ((u32)f2bf((acc[i2][2][3] + kv[2][3]) * dd) << 16);
                *(uint2*)(hp + 32) = p;
            }
        }
    }
}

// --- gather layer 2: out[n] = logsoftmax(dinv[n]*sum h2s[s] + b2), 16 ln/node
__global__ __launch_bounds__(256) void gather2_fused(const int* __restrict__ cnt_pad,
                                                     const int* __restrict__ ell,
                                                     const float* __restrict__ dinv,
                                                     const u16* __restrict__ h2s,
                                                     const float* __restrict__ b2,
                                                     float* __restrict__ out) {
    int node = blockIdx.x * 16 + (threadIdx.x >> 4);     // grid exact: N%16==0
    int q = threadIdx.x & 15;
    int len = cnt_pad[node * CNT_STRIDE];
    if (len > ELL_W) len = ELL_W;
    const int* rowp = ell + node * ELL_W;
    float a0 = 0.f, a1 = 0.f, a2 = 0.f, a3 = 0.f;
    int e = 0;
    for (; e + 3 < len; e += 4) {
        int s0 = rowp[e], s1 = rowp[e + 1], s2 = rowp[e + 2], s3 = rowp[e + 3];
        if (q < 10) {
            uint2 v0 = *(const uint2*)(h2s + (size_t)s0 * C_OUT + q * 4);
            uint2 v1 = *(const uint2*)(h2s + (size_t)s1 * C_OUT + q * 4);
            uint2 v2 = *(const uint2*)(h2s + (size_t)s2 * C_OUT + q * 4);
            uint2 v3 = *(const uint2*)(h2s + (size_t)s3 * C_OUT + q * 4);
            add2(&a0, &a1, v0.x); add2(&a2, &a3, v0.y);
            add2(&a0, &a1, v1.x); add2(&a2, &a3, v1.y);
            add2(&a0, &a1, v2.x); add2(&a2, &a3, v2.y);
            add2(&a0, &a1, v3.x); add2(&a2, &a3, v3.y);
        }
    }
    for (; e < len; ++e) {
        int s = rowp[e];
        if (q < 10) {
            uint2 v = *(const uint2*)(h2s + (size_t)s * C_OUT + q * 4);
            add2(&a0, &a1, v.x); add2(&a2, &a3, v.y);
        }
    }
    float dd = dinv[node];
    float4 r;
    float m = -INFINITY;
    if (q < 10) {
        float4 bv = *(const float4*)(b2 + q * 4);
        r.x = fmaf(a0, dd, bv.x); r.y = fmaf(a1, dd, bv.y);
        r.z = fmaf(a2, dd, bv.z); r.w = fmaf(a3, dd, bv.w);
        m = fmaxf(fmaxf(r.x, r.y), fmaxf(r.z, r.w));
    }
    #pragma unroll
    for (int off = 1; off < 16; off <<= 1) m = fmaxf(m, __shfl_xor(m, off, 16));
    float ex = 0.f;
    if (q < 10)
        ex = expf(r.x - m) + expf(r.y - m) + expf(r.z - m) + expf(r.w - m);
    #pragma unroll
    for (int off = 1; off < 16; off <<= 1) ex += __shfl_xor(ex, off, 16);
    float lse = logf(ex) + m;
    if (q < 10) {
        float4 o = {r.x - lse, r.y - lse, r.z - lse, r.w - lse};
        *(float4*)(out + (size_t)node * C_OUT + q * 4) = o;
    }
}

// ---------------- launch ----------------
extern "C" void kernel_launch(void* const* d_in, const int* in_sizes, int n_in,
                              void* d_out, int out_size, void* d_ws, size_t ws_size,
                              hipStream_t stream) {
    const float* x     = (const float*)d_in[0];
    const int*   eidx  = (const int*)d_in[1];
    const float* W1    = (const float*)d_in[2];
    const float* b1    = (const float*)d_in[3];
    const float* gamma = (const float*)d_in[4];
    const float* beta  = (const float*)d_in[5];
    const float* W2    = (const float*)d_in[6];
    const float* b2    = (const float*)d_in[7];
    float* out = (float*)d_out;

    const int* src = eidx;
    const int* dst = eidx + N_EDGES;

    // workspace layout (4B units)
    float* ws = (float*)d_ws;
    int*   cnt_pad = (int*)ws;                 // N*16 (1 counter / 64B line)
    float* dinv    = ws + 1600000;             // N
    int*   ell     = (int*)(ws + 1700000);     // N*64
    u16*   xs      = (u16*)(ws + 8100000);     // N*128 bf16; hb aliases (xs dead after gather_x)
    u16*   hb      = (u16*)(ws + 8100000);
    u16*   aggb    = (u16*)(ws + 14500000);    // N*128 bf16
    u16*   W1t     = (u16*)(ws + 20900000);    // 128*128 bf16
    u16*   h2s     = (u16*)(ws + 20908192);    // N*40 bf16 (dinv-scaled h2)
    float* pstats  = ws + 22908192;            // 256*800 f32
    float* scale   = ws + 23112992;            // 128
    float* shift   = ws + 23113120;            // 128
    float* K       = ws + 23113248;            // 48 (+pad)
    u16*   W2t     = (u16*)(ws + 23113312);    // 48*128 bf16

    size_t needed = (size_t)(23113312 + 3072) * 4;   // ~92.5 MB
    if (ws_size < needed) return;

    // ELL build (padded counters; fused count+fill; no scans)
    ell_init<<<(N_NODES + 255) / 256, 256, 0, stream>>>(cnt_pad, ell);
    ell_fill<<<(N_EDGES + 255) / 256, 256, 0, stream>>>(src, dst, cnt_pad, ell);
    dinv_k<<<(N_NODES + 255) / 256, 256, 0, stream>>>(cnt_pad, dinv);

    // layer 1
    xconvert<<<N_NODES * F_IN / 4 / 256, 256, 0, stream>>>(x, dinv, xs);
    wconvert<<<F_IN * H_DIM / 256, 256, 0, stream>>>(W1, W1t);
    gather_x<<<N_NODES / 16, 256, 0, stream>>>(cnt_pad, ell, dinv, xs, aggb);
    gemm1_mfma<<<G1_NB, 256, 0, stream>>>(aggb, W1t, b1, hb, pstats);
    stats_final<<<128, 256, 0, stream>>>(pstats, gamma, beta, scale, shift);
    w2fold<<<1, 256, 0, stream>>>(W2, scale, shift, W2t, K);

    // layer 2
    gemm2_mfma<<<G1_NB, 256, 0, stream>>>(hb, W2t, K, dinv, h2s);
    gather2_fused<<<N_NODES / 16, 256, 0, stream>>>(cnt_pad, ell, dinv, h2s, b2, out);
}

// Round 8
// 217.678 us; speedup vs baseline: 1.3547x; 1.3547x over previous
//
#include <hip/hip_runtime.h>
#include <math.h>

#define N_NODES 100000
#define N_EDGES 1600000
#define F_IN 128
#define H_DIM 128
#define C_OUT 40
#define BN_EPS 1e-5f

#define ELL_W 64           // slots per node; Poisson(16) => P(deg>63) ~ 1e-17
#define CNT_STRIDE 16      // bcur padding: one cursor per 64B line

#define BKT_W 512          // nodes per coarse bucket
#define NBKT ((N_NODES + BKT_W - 1) / BKT_W)            // 196
#define BKT_CAP 12288      // edges capacity per bucket (mean 8163, +45 sigma)
#define P_EDGES 2048       // edges per scatter block
#define P_NB ((N_EDGES + P_EDGES - 1) / P_EDGES)        // 782

#define G1_ROWS 128
#define G1_LD 136          // shorts: 272 B row
#define G1_NB ((N_NODES + G1_ROWS - 1) / G1_ROWS)       // 782
#define PS_LD 800          // pstats stride (>= G1_NB)

typedef unsigned short u16;
typedef unsigned int u32;
typedef __attribute__((ext_vector_type(8))) __bf16 bf16x8;
typedef __attribute__((ext_vector_type(4))) float f32x4;

__device__ __forceinline__ u16 f2bf(float f) {              // RNE
    u32 u = __float_as_uint(f);
    u += 0x7FFFu + ((u >> 16) & 1u);
    return (u16)(u >> 16);
}
__device__ __forceinline__ float bf2f(u16 h) {
    return __uint_as_float(((u32)h) << 16);
}
// packed dword of 2 bf16 -> two f32 adds (2 VALU each)
__device__ __forceinline__ void add2(float* a0, float* a1, u32 d) {
    *a0 += __uint_as_float(d << 16);
    *a1 += __uint_as_float(d & 0xFFFF0000u);
}

// ---- pass 1: bucket edges by dst>>9 into per-bucket regions (coalesced-ish)
__global__ __launch_bounds__(256) void bucket_scatter(const int* __restrict__ src,
                                                      const int* __restrict__ dst,
                                                      int* __restrict__ bcur,
                                                      int2* __restrict__ region) {
    __shared__ int lcnt[NBKT];
    __shared__ int gofs[NBKT];
    int t = threadIdx.x;
    for (int i = t; i < NBKT; i += 256) lcnt[i] = 0;
    __syncthreads();
    int base = blockIdx.x * P_EDGES;
    int d[8], bk[8];
    #pragma unroll
    for (int i = 0; i < 8; ++i) {
        int idx = base + i * 256 + t;
        if (idx < N_EDGES) {
            d[i] = dst[idx];
            bk[i] = d[i] >> 9;
            atomicAdd(&lcnt[bk[i]], 1);
        } else d[i] = -1;
    }
    __syncthreads();
    for (int i = t; i < NBKT; i += 256) {
        int c = lcnt[i];
        gofs[i] = c ? atomicAdd(&bcur[i * CNT_STRIDE], c) : 0;
        lcnt[i] = 0;                      // reuse as local rank counter
    }
    __syncthreads();
    #pragma unroll
    for (int i = 0; i < 8; ++i) {
        int idx = base + i * 256 + t;
        if (idx < N_EDGES) {
            int rank = atomicAdd(&lcnt[bk[i]], 1);
            int pos = gofs[bk[i]] + rank;
            if (pos < BKT_CAP)            // statistically impossible; guards OOB
                region[(size_t)bk[i] * BKT_CAP + pos] = make_int2(src[idx], d[i]);
        }
    }
}

// ---- pass 2: per-bucket ELL build; scatter confined to a 128KB window ----
__global__ __launch_bounds__(256) void ell_build(const int* __restrict__ bcur,
                                                 const int2* __restrict__ region,
                                                 int* __restrict__ ell,
                                                 int* __restrict__ cnt,
                                                 float* __restrict__ dinv) {
    __shared__ int lcnt[BKT_W];
    int b = blockIdx.x, t = threadIdx.x;
    int nbase = b * BKT_W;
    for (int i = t; i < BKT_W; i += 256) {
        lcnt[i] = 1;                      // self-loop occupies slot 0
        int node = nbase + i;
        if (node < N_NODES) ell[(size_t)node * ELL_W] = node;
    }
    __syncthreads();
    int ne = bcur[b * CNT_STRIDE];
    if (ne > BKT_CAP) ne = BKT_CAP;
    const int2* reg = region + (size_t)b * BKT_CAP;
    for (int i = t; i < ne; i += 256) {
        int2 p = reg[i];
        int rank = atomicAdd(&lcnt[p.y - nbase], 1);
        if (rank < ELL_W) ell[(size_t)p.y * ELL_W + rank] = p.x;
    }
    __syncthreads();
    for (int i = t; i < BKT_W; i += 256) {
        int node = nbase + i;
        if (node < N_NODES) {
            int c = lcnt[i];
            cnt[node] = (c > ELL_W) ? ELL_W : c;
            dinv[node] = rsqrtf((float)c);   // true degree
        }
    }
}

// ---------------- xs = dinv[n] * x (bf16, RNE) ----------------
__global__ __launch_bounds__(256) void xconvert(const float* __restrict__ x,
                                                const float* __restrict__ dinv,
                                                u16* __restrict__ xs) {
    int i = blockIdx.x * 256 + threadIdx.x;      // exactly 3.2M threads (float4 units)
    int n = i >> 5;                              // 32 float4 per row
    float dd = dinv[n];
    float4 v = ((const float4*)x)[i];
    ushort4 o;
    o.x = f2bf(v.x * dd); o.y = f2bf(v.y * dd);
    o.z = f2bf(v.z * dd); o.w = f2bf(v.w * dd);
    ((ushort4*)xs)[i] = o;
}

// W1 [k][n] f32 -> W1t [n][k] bf16
__global__ __launch_bounds__(256) void wconvert(const float* __restrict__ W1,
                                                u16* __restrict__ W1t) {
    int i = blockIdx.x * 256 + threadIdx.x;      // 16384
    int k = i >> 7, n = i & 127;
    W1t[n * H_DIM + k] = f2bf(W1[k * H_DIM + n]);
}

// ------- gather layer 1: aggb[n] = bf16( dinv[n] * sum_{s in N(n)} xs[s] ) --
// 16 lanes/node (8 ch each, int4), 16 nodes/block, 4-edge unroll.
__global__ __launch_bounds__(256) void gather_x(const int* __restrict__ cnt,
                                                const int* __restrict__ ell,
                                                const float* __restrict__ dinv,
                                                const u16* __restrict__ xs,
                                                u16* __restrict__ aggb) {
    int node = blockIdx.x * 16 + (threadIdx.x >> 4);     // grid exact: N%16==0
    int q = threadIdx.x & 15;
    int len = cnt[node];
    const int* row = ell + (size_t)node * ELL_W;
    float acc[8] = {};
    int e = 0;
    for (; e + 3 < len; e += 4) {
        int s0 = row[e], s1 = row[e + 1], s2 = row[e + 2], s3 = row[e + 3];
        int4 v0 = *(const int4*)(xs + (size_t)s0 * F_IN + q * 8);
        int4 v1 = *(const int4*)(xs + (size_t)s1 * F_IN + q * 8);
        int4 v2 = *(const int4*)(xs + (size_t)s2 * F_IN + q * 8);
        int4 v3 = *(const int4*)(xs + (size_t)s3 * F_IN + q * 8);
        add2(&acc[0], &acc[1], (u32)v0.x); add2(&acc[2], &acc[3], (u32)v0.y);
        add2(&acc[4], &acc[5], (u32)v0.z); add2(&acc[6], &acc[7], (u32)v0.w);
        add2(&acc[0], &acc[1], (u32)v1.x); add2(&acc[2], &acc[3], (u32)v1.y);
        add2(&acc[4], &acc[5], (u32)v1.z); add2(&acc[6], &acc[7], (u32)v1.w);
        add2(&acc[0], &acc[1], (u32)v2.x); add2(&acc[2], &acc[3], (u32)v2.y);
        add2(&acc[4], &acc[5], (u32)v2.z); add2(&acc[6], &acc[7], (u32)v2.w);
        add2(&acc[0], &acc[1], (u32)v3.x); add2(&acc[2], &acc[3], (u32)v3.y);
        add2(&acc[4], &acc[5], (u32)v3.z); add2(&acc[6], &acc[7], (u32)v3.w);
    }
    for (; e < len; ++e) {
        int s = row[e];
        int4 v = *(const int4*)(xs + (size_t)s * F_IN + q * 8);
        add2(&acc[0], &acc[1], (u32)v.x); add2(&acc[2], &acc[3], (u32)v.y);
        add2(&acc[4], &acc[5], (u32)v.z); add2(&acc[6], &acc[7], (u32)v.w);
    }
    float dd = dinv[node];
    int4 o;
    o.x = (int)((u32)f2bf(acc[0] * dd) | ((u32)f2bf(acc[1] * dd) << 16));
    o.y = (int)((u32)f2bf(acc[2] * dd) | ((u32)f2bf(acc[3] * dd) << 16));
    o.z = (int)((u32)f2bf(acc[4] * dd) | ((u32)f2bf(acc[5] * dd) << 16));
    o.w = (int)((u32)f2bf(acc[6] * dd) | ((u32)f2bf(acc[7] * dd) << 16));
    *(int4*)(aggb + (size_t)node * H_DIM + q * 8) = o;
}

// ------------- GEMM1 via MFMA: hb = relu(aggb@W1 + b1) (bf16) --------------
__global__ __launch_bounds__(256) void gemm1_mfma(const u16* __restrict__ aggb,
                                                  const u16* __restrict__ W1t,
                                                  const float* __restrict__ b1,
                                                  u16* __restrict__ hb,
                                                  float* __restrict__ pstats) {
    __shared__ u16 As[G1_ROWS * G1_LD];   // 34.8 KB
    int tid = threadIdx.x;
    int base = blockIdx.x * G1_ROWS;

    {   // stage 128 node rows (256 B each), clamped at tail
        int row = tid >> 1, half = tid & 1;
        int gr = base + row; if (gr >= N_NODES) gr = N_NODES - 1;
        const int4* gsrc = (const int4*)(aggb + (size_t)gr * H_DIM + half * 64);
        int4* ldst = (int4*)(As + row * G1_LD + half * 64);
        #pragma unroll
        for (int i = 0; i < 8; ++i) ldst[i] = gsrc[i];
    }
    __syncthreads();

    int lane = tid & 63, w = tid >> 6;
    int r = lane & 15, g = lane >> 4;

    bf16x8 wf[2][4];   // [ch-tile][kstep], resident
    #pragma unroll
    for (int t = 0; t < 2; ++t)
        #pragma unroll
        for (int ks = 0; ks < 4; ++ks)
            wf[t][ks] = *(const bf16x8*)(W1t + (w * 32 + t * 16 + r) * H_DIM + ks * 32 + g * 8);

    float bch[2][4];
    #pragma unroll
    for (int t = 0; t < 2; ++t)
        #pragma unroll
        for (int i = 0; i < 4; ++i)
            bch[t][i] = b1[w * 32 + t * 16 + 4 * g + i];

    float cs[8] = {}, cq[8] = {};

    for (int rt = 0; rt < 8; ++rt) {
        f32x4 acc0 = {0.f, 0.f, 0.f, 0.f}, acc1 = {0.f, 0.f, 0.f, 0.f};
        #pragma unroll
        for (int ks = 0; ks < 4; ++ks) {
            bf16x8 nf = *(const bf16x8*)(As + (rt * 16 + r) * G1_LD + ks * 32 + g * 8);
            acc0 = __builtin_amdgcn_mfma_f32_16x16x32_bf16(wf[0][ks], nf, acc0, 0, 0, 0);
            acc1 = __builtin_amdgcn_mfma_f32_16x16x32_bf16(wf[1][ks], nf, acc1, 0, 0, 0);
        }
        int node = base + rt * 16 + r;
        if (node < N_NODES) {
            float o0[4], o1[4];
            #pragma unroll
            for (int i = 0; i < 4; ++i) {
                o0[i] = fmaxf(acc0[i] + bch[0][i], 0.f);
                o1[i] = fmaxf(acc1[i] + bch[1][i], 0.f);
                cs[i]     += o0[i]; cq[i]     += o0[i] * o0[i];
                cs[4 + i] += o1[i]; cq[4 + i] += o1[i] * o1[i];
            }
            uint2 p0, p1;
            p0.x = (u32)f2bf(o0[0]) | ((u32)f2bf(o0[1]) << 16);
            p0.y = (u32)f2bf(o0[2]) | ((u32)f2bf(o0[3]) << 16);
            p1.x = (u32)f2bf(o1[0]) | ((u32)f2bf(o1[1]) << 16);
            p1.y = (u32)f2bf(o1[2]) | ((u32)f2bf(o1[3]) << 16);
            u16* hp = hb + (size_t)node * H_DIM + w * 32 + 4 * g;
            *(uint2*)hp = p0;
            *(uint2*)(hp + 16) = p1;
        }
    }

    #pragma unroll
    for (int j = 0; j < 8; ++j) {
        #pragma unroll
        for (int m = 1; m < 16; m <<= 1) {
            cs[j] += __shfl_xor(cs[j], m, 16);
            cq[j] += __shfl_xor(cq[j], m, 16);
        }
    }
    if (r == 0) {
        #pragma unroll
        for (int j = 0; j < 8; ++j) {
            int c = w * 32 + (j >> 2) * 16 + 4 * g + (j & 3);
            pstats[c * PS_LD + blockIdx.x] = cs[j];
            pstats[(128 + c) * PS_LD + blockIdx.x] = cq[j];
        }
    }
}

// ---- reduce per-block partials -> scale/shift (one block per channel) ----
__global__ __launch_bounds__(256) void stats_final(const float* __restrict__ pstats,
                                                   const float* __restrict__ gamma,
                                                   const float* __restrict__ beta,
                                                   float* __restrict__ scale,
                                                   float* __restrict__ shift) {
    __shared__ float ls[256], lq[256];
    int c = blockIdx.x, t = threadIdx.x;
    float s = 0.f, q = 0.f;
    for (int b = t; b < G1_NB; b += 256) {
        s += pstats[c * PS_LD + b];
        q += pstats[(128 + c) * PS_LD + b];
    }
    ls[t] = s; lq[t] = q;
    __syncthreads();
    for (int off = 128; off; off >>= 1) {
        if (t < off) { ls[t] += ls[t + off]; lq[t] += lq[t + off]; }
        __syncthreads();
    }
    if (t == 0) {
        const float invn = 1.0f / (float)N_NODES;
        float mean = ls[0] * invn;
        float var = lq[0] * invn - mean * mean;
        float sc = gamma[c] * rsqrtf(var + BN_EPS);
        scale[c] = sc;
        shift[c] = beta[c] - mean * sc;
    }
}

// ---- fold BN into layer-2 weights; K[c] = sum_k shift[k]*W2[k][c] ----
__global__ __launch_bounds__(256) void w2fold(const float* __restrict__ W2,
                                              const float* __restrict__ scale,
                                              const float* __restrict__ shift,
                                              u16* __restrict__ W2t,
                                              float* __restrict__ K) {
    int t = threadIdx.x;
    for (int i = t; i < 48 * 128; i += 256) {
        int c = i >> 7, k = i & 127;
        W2t[i] = (c < C_OUT) ? f2bf(scale[k] * W2[k * C_OUT + c]) : (u16)0;
    }
    if (t < 48) {
        float a = 0.f;
        if (t < C_OUT)
            for (int k = 0; k < H_DIM; ++k) a += shift[k] * W2[k * C_OUT + t];
        K[t] = a;
    }
}

// ---- GEMM2 via MFMA: h2s[n] = bf16( dinv[n] * (hb[n]@W2t + K) )  (48 ch) ---
__global__ __launch_bounds__(256) void gemm2_mfma(const u16* __restrict__ hb,
                                                  const u16* __restrict__ W2t,
                                                  const float* __restrict__ K,
                                                  const float* __restrict__ dinv,
                                                  u16* __restrict__ h2s) {
    __shared__ u16 As[G1_ROWS * G1_LD];
    int tid = threadIdx.x;
    int base = blockIdx.x * G1_ROWS;

    {
        int row = tid >> 1, half = tid & 1;
        int gr = base + row; if (gr >= N_NODES) gr = N_NODES - 1;
        const int4* gsrc = (const int4*)(hb + (size_t)gr * H_DIM + half * 64);
        int4* ldst = (int4*)(As + row * G1_LD + half * 64);
        #pragma unroll
        for (int i = 0; i < 8; ++i) ldst[i] = gsrc[i];
    }
    __syncthreads();

    int lane = tid & 63, w = tid >> 6;
    int r = lane & 15, g = lane >> 4;

    bf16x8 wf[3][4];
    #pragma unroll
    for (int t = 0; t < 3; ++t)
        #pragma unroll
        for (int ks = 0; ks < 4; ++ks)
            wf[t][ks] = *(const bf16x8*)(W2t + (t * 16 + r) * H_DIM + ks * 32 + g * 8);

    float kv[3][4];
    #pragma unroll
    for (int t = 0; t < 3; ++t)
        #pragma unroll
        for (int i = 0; i < 4; ++i)
            kv[t][i] = K[t * 16 + 4 * g + i];

    f32x4 acc[2][3];
    #pragma unroll
    for (int i2 = 0; i2 < 2; ++i2)
        #pragma unroll
        for (int t = 0; t < 3; ++t)
            acc[i2][t] = (f32x4){0.f, 0.f, 0.f, 0.f};

    #pragma unroll
    for (int i2 = 0; i2 < 2; ++i2) {
        int rt = 2 * w + i2;
        #pragma unroll
        for (int ks = 0; ks < 4; ++ks) {
            bf16x8 nf = *(const bf16x8*)(As + (rt * 16 + r) * G1_LD + ks * 32 + g * 8);
            acc[i2][0] = __builtin_amdgcn_mfma_f32_16x16x32_bf16(wf[0][ks], nf, acc[i2][0], 0, 0, 0);
            acc[i2][1] = __builtin_amdgcn_mfma_f32_16x16x32_bf16(wf[1][ks], nf, acc[i2][1], 0, 0, 0);
            acc[i2][2] = __builtin_amdgcn_mfma_f32_16x16x32_bf16(wf[2][ks], nf, acc[i2][2], 0, 0, 0);
        }
    }

    #pragma unroll
    for (int i2 = 0; i2 < 2; ++i2) {
        int node = base + (2 * w + i2) * 16 + r;
        if (node < N_NODES) {
            float dd = dinv[node];
            u16* hp = h2s + (size_t)node * C_OUT + 4 * g;
            #pragma unroll
            for (int t = 0; t < 2; ++t) {
                uint2 p;
                p.x = (u32)f2bf((acc[i2][t][0] + kv[t][0]) * dd) |
                      ((u32)f2bf((acc[i2][t][1] + kv[t][1]) * dd) << 16);
                p.y = (u32)f2bf((acc[i2][t][2] + kv[t][2]) * dd) |
                      ((u32)f2bf((acc[i2][t][3] + kv[t][3]) * dd) << 16);
                *(uint2*)(hp + t * 16) = p;
            }
            if (g < 2) {
                uint2 p;
                p.x = (u32)f2bf((acc[i2][2][0] + kv[2][0]) * dd) |
                      ((u32)f2bf((acc[i2][2][1] + kv[2][1]) * dd) << 16);
                p.y = (u32)f2bf((acc[i2][2][2] + kv[2][2]) * dd) |
                      ((u32)f2bf((acc[i2][2][3] + kv[2][3]) * dd) << 16);
                *(uint2*)(hp + 32) = p;
            }
        }
    }
}

// --- gather layer 2: out[n] = logsoftmax(dinv[n]*sum h2s[s] + b2), 16 ln/node
__global__ __launch_bounds__(256) void gather2_fused(const int* __restrict__ cnt,
                                                     const int* __restrict__ ell,
                                                     const float* __restrict__ dinv,
                                                     const u16* __restrict__ h2s,
                                                     const float* __restrict__ b2,
                                                     float* __restrict__ out) {
    int node = blockIdx.x * 16 + (threadIdx.x >> 4);     // grid exact: N%16==0
    int q = threadIdx.x & 15;
    int len = cnt[node];
    const int* rowp = ell + (size_t)node * ELL_W;
    float a0 = 0.f, a1 = 0.f, a2 = 0.f, a3 = 0.f;
    int e = 0;
    for (; e + 3 < len; e += 4) {
        int s0 = rowp[e], s1 = rowp[e + 1], s2 = rowp[e + 2], s3 = rowp[e + 3];
        if (q < 10) {
            uint2 v0 = *(const uint2*)(h2s + (size_t)s0 * C_OUT + q * 4);
            uint2 v1 = *(const uint2*)(h2s + (size_t)s1 * C_OUT + q * 4);
            uint2 v2 = *(const uint2*)(h2s + (size_t)s2 * C_OUT + q * 4);
            uint2 v3 = *(const uint2*)(h2s + (size_t)s3 * C_OUT + q * 4);
            add2(&a0, &a1, v0.x); add2(&a2, &a3, v0.y);
            add2(&a0, &a1, v1.x); add2(&a2, &a3, v1.y);
            add2(&a0, &a1, v2.x); add2(&a2, &a3, v2.y);
            add2(&a0, &a1, v3.x); add2(&a2, &a3, v3.y);
        }
    }
    for (; e < len; ++e) {
        int s = rowp[e];
        if (q < 10) {
            uint2 v = *(const uint2*)(h2s + (size_t)s * C_OUT + q * 4);
            add2(&a0, &a1, v.x); add2(&a2, &a3, v.y);
        }
    }
    float dd = dinv[node];
    float4 r;
    float m = -INFINITY;
    if (q < 10) {
        float4 bv = *(const float4*)(b2 + q * 4);
        r.x = fmaf(a0, dd, bv.x); r.y = fmaf(a1, dd, bv.y);
        r.z = fmaf(a2, dd, bv.z); r.w = fmaf(a3, dd, bv.w);
        m = fmaxf(fmaxf(r.x, r.y), fmaxf(r.z, r.w));
    }
    #pragma unroll
    for (int off = 1; off < 16; off <<= 1) m = fmaxf(m, __shfl_xor(m, off, 16));
    float ex = 0.f;
    if (q < 10)
        ex = expf(r.x - m) + expf(r.y - m) + expf(r.z - m) + expf(r.w - m);
    #pragma unroll
    for (int off = 1; off < 16; off <<= 1) ex += __shfl_xor(ex, off, 16);
    float lse = logf(ex) + m;
    if (q < 10) {
        float4 o = {r.x - lse, r.y - lse, r.z - lse, r.w - lse};
        *(float4*)(out + (size_t)node * C_OUT + q * 4) = o;
    }
}

// ---------------- launch ----------------
extern "C" void kernel_launch(void* const* d_in, const int* in_sizes, int n_in,
                              void* d_out, int out_size, void* d_ws, size_t ws_size,
                              hipStream_t stream) {
    const float* x     = (const float*)d_in[0];
    const int*   eidx  = (const int*)d_in[1];
    const float* W1    = (const float*)d_in[2];
    const float* b1    = (const float*)d_in[3];
    const float* gamma = (const float*)d_in[4];
    const float* beta  = (const float*)d_in[5];
    const float* W2    = (const float*)d_in[6];
    const float* b2    = (const float*)d_in[7];
    float* out = (float*)d_out;

    const int* src = eidx;
    const int* dst = eidx + N_EDGES;

    // workspace layout (dword units)
    float* ws = (float*)d_ws;
    float* dinv    = ws;                        // N
    int*   cnt     = (int*)(ws + 100000);       // N
    int*   bcur    = (int*)(ws + 200000);       // NBKT*16 = 3136 (+pad)
    int*   ell     = (int*)(ws + 203200);       // N*64 = 6.4M
    u16*   xs      = (u16*)(ws + 6603200);      // N*128 bf16 (6.4M dwords); hb aliases
    u16*   hb      = (u16*)(ws + 6603200);
    u16*   aggb    = (u16*)(ws + 13003200);     // N*128 bf16; region aliases (dead before aggb written)
    int2*  region  = (int2*)(ws + 13003200);    // NBKT*BKT_CAP int2 = 4.82M dwords < 6.4M
    u16*   W1t     = (u16*)(ws + 19403200);     // 128*128 bf16
    u16*   h2s     = (u16*)(ws + 19411392);     // N*40 bf16 (dinv-scaled h2) = 2M dwords
    float* pstats  = ws + 21411392;             // 256*800 f32
    float* scale   = ws + 21616192;             // 128
    float* shift   = ws + 21616320;             // 128
    float* K       = ws + 21616448;             // 48 (+pad)
    u16*   W2t     = (u16*)(ws + 21616512);     // 48*128 bf16 = 3072 dwords

    size_t needed = (size_t)(21616512 + 3200) * 4;   // ~86.5 MB (< 99.2 MB proven)
    if (ws_size < needed) return;

    // graph build: bucket scatter + per-bucket ELL build (no global scans)
    hipMemsetAsync(bcur, 0, NBKT * CNT_STRIDE * 4, stream);
    bucket_scatter<<<P_NB, 256, 0, stream>>>(src, dst, bcur, region);
    ell_build<<<NBKT, 256, 0, stream>>>(bcur, region, ell, cnt, dinv);

    // layer 1
    xconvert<<<N_NODES * F_IN / 4 / 256, 256, 0, stream>>>(x, dinv, xs);
    wconvert<<<F_IN * H_DIM / 256, 256, 0, stream>>>(W1, W1t);
    gather_x<<<N_NODES / 16, 256, 0, stream>>>(cnt, ell, dinv, xs, aggb);
    gemm1_mfma<<<G1_NB, 256, 0, stream>>>(aggb, W1t, b1, hb, pstats);
    stats_final<<<128, 256, 0, stream>>>(pstats, gamma, beta, scale, shift);
    w2fold<<<1, 256, 0, stream>>>(W2, scale, shift, W2t, K);

    // layer 2
    gemm2_mfma<<<G1_NB, 256, 0, stream>>>(hb, W2t, K, dinv, h2s);
    gather2_fused<<<N_NODES / 16, 256, 0, stream>>>(cnt, ell, dinv, h2s, b2, out);
}

// Round 9
// 216.678 us; speedup vs baseline: 1.3610x; 1.0046x over previous
//
#include <hip/hip_runtime.h>
#include <math.h>

#define N_NODES 100000
#define N_EDGES 1600000
#define F_IN 128
#define H_DIM 128
#define C_OUT 40
#define BN_EPS 1e-5f

#define ELL_W 64           // slots per node; Poisson(16) => P(deg>63) ~ 1e-17
#define CNT_STRIDE 16      // bcur padding: one cursor per 64B line

#define BKT_W 512          // nodes per coarse bucket
#define NBKT ((N_NODES + BKT_W - 1) / BKT_W)            // 196
#define BKT_CAP 12288      // edges capacity per bucket (mean 8163, +45 sigma)
#define P_EDGES 2048       // edges per scatter block
#define P_NB ((N_EDGES + P_EDGES - 1) / P_EDGES)        // 782

#define G1_ROWS 64
#define G1_LD 136          // shorts: 272 B row
#define G1_NB ((N_NODES + G1_ROWS - 1) / G1_ROWS)       // 1563
#define PS_LD 1600         // pstats stride (>= G1_NB)
#define G2_ROWS 128
#define G2_NB ((N_NODES + G2_ROWS - 1) / G2_ROWS)       // 782

typedef unsigned short u16;
typedef unsigned int u32;
typedef __attribute__((ext_vector_type(8))) __bf16 bf16x8;
typedef __attribute__((ext_vector_type(4))) float f32x4;

__device__ __forceinline__ u16 f2bf(float f) {              // RNE
    u32 u = __float_as_uint(f);
    u += 0x7FFFu + ((u >> 16) & 1u);
    return (u16)(u >> 16);
}
__device__ __forceinline__ float bf2f(u16 h) {
    return __uint_as_float(((u32)h) << 16);
}
// packed dword of 2 bf16 -> two f32 adds (2 VALU each)
__device__ __forceinline__ void add2(float* a0, float* a1, u32 d) {
    *a0 += __uint_as_float(d << 16);
    *a1 += __uint_as_float(d & 0xFFFF0000u);
}
#define ACC4(v) do { add2(&acc[0],&acc[1],(u32)(v).x); add2(&acc[2],&acc[3],(u32)(v).y); \
                     add2(&acc[4],&acc[5],(u32)(v).z); add2(&acc[6],&acc[7],(u32)(v).w); } while(0)

// ---- pass 1: bucket edges by dst>>9 into per-bucket regions (coalesced-ish)
__global__ __launch_bounds__(256) void bucket_scatter(const int* __restrict__ src,
                                                      const int* __restrict__ dst,
                                                      int* __restrict__ bcur,
                                                      int2* __restrict__ region) {
    __shared__ int lcnt[NBKT];
    __shared__ int gofs[NBKT];
    int t = threadIdx.x;
    for (int i = t; i < NBKT; i += 256) lcnt[i] = 0;
    __syncthreads();
    int base = blockIdx.x * P_EDGES;
    int d[8], bk[8];
    #pragma unroll
    for (int i = 0; i < 8; ++i) {
        int idx = base + i * 256 + t;
        if (idx < N_EDGES) {
            d[i] = dst[idx];
            bk[i] = d[i] >> 9;
            atomicAdd(&lcnt[bk[i]], 1);
        } else d[i] = -1;
    }
    __syncthreads();
    for (int i = t; i < NBKT; i += 256) {
        int c = lcnt[i];
        gofs[i] = c ? atomicAdd(&bcur[i * CNT_STRIDE], c) : 0;
        lcnt[i] = 0;                      // reuse as local rank counter
    }
    __syncthreads();
    #pragma unroll
    for (int i = 0; i < 8; ++i) {
        int idx = base + i * 256 + t;
        if (idx < N_EDGES) {
            int rank = atomicAdd(&lcnt[bk[i]], 1);
            int pos = gofs[bk[i]] + rank;
            if (pos < BKT_CAP)            // statistically impossible; guards OOB
                region[(size_t)bk[i] * BKT_CAP + pos] = make_int2(src[idx], d[i]);
        }
    }
}

// ---- pass 2: per-bucket ELL build; scatter confined to a 128KB window ----
__global__ __launch_bounds__(256) void ell_build(const int* __restrict__ bcur,
                                                 const int2* __restrict__ region,
                                                 int* __restrict__ ell,
                                                 int* __restrict__ cnt,
                                                 float* __restrict__ dinv) {
    __shared__ int lcnt[BKT_W];
    int b = blockIdx.x, t = threadIdx.x;
    int nbase = b * BKT_W;
    for (int i = t; i < BKT_W; i += 256) {
        lcnt[i] = 1;                      // self-loop occupies slot 0
        int node = nbase + i;
        if (node < N_NODES) ell[(size_t)node * ELL_W] = node;
    }
    __syncthreads();
    int ne = bcur[b * CNT_STRIDE];
    if (ne > BKT_CAP) ne = BKT_CAP;
    const int2* reg = region + (size_t)b * BKT_CAP;
    for (int i = t; i < ne; i += 256) {
        int2 p = reg[i];
        int rank = atomicAdd(&lcnt[p.y - nbase], 1);
        if (rank < ELL_W) ell[(size_t)p.y * ELL_W + rank] = p.x;
    }
    __syncthreads();
    for (int i = t; i < BKT_W; i += 256) {
        int node = nbase + i;
        if (node < N_NODES) {
            int c = lcnt[i];
            cnt[node] = (c > ELL_W) ? ELL_W : c;
            dinv[node] = rsqrtf((float)c);   // true degree
        }
    }
}

// ---------------- xs = dinv[n] * x (bf16, RNE) ----------------
__global__ __launch_bounds__(256) void xconvert(const float* __restrict__ x,
                                                const float* __restrict__ dinv,
                                                u16* __restrict__ xs) {
    int i = blockIdx.x * 256 + threadIdx.x;      // exactly 3.2M threads (float4 units)
    int n = i >> 5;                              // 32 float4 per row
    float dd = dinv[n];
    float4 v = ((const float4*)x)[i];
    ushort4 o;
    o.x = f2bf(v.x * dd); o.y = f2bf(v.y * dd);
    o.z = f2bf(v.z * dd); o.w = f2bf(v.w * dd);
    ((ushort4*)xs)[i] = o;
}

// W1 [k][n] f32 -> W1t [n][k] bf16
__global__ __launch_bounds__(256) void wconvert(const float* __restrict__ W1,
                                                u16* __restrict__ W1t) {
    int i = blockIdx.x * 256 + threadIdx.x;      // 16384
    int k = i >> 7, n = i & 127;
    W1t[n * H_DIM + k] = f2bf(W1[k * H_DIM + n]);
}

// ---- FUSED layer 1: gather 64-node tile into LDS, then MFMA + relu + stats -
// Gather: 16 lanes/node (8 ch each, int4), 16 nodes in parallel, 4 rounds,
// 8-edge unroll. MFMA: wave w owns channels [32w,32w+32), 4 row-tiles.
__global__ __launch_bounds__(256) void fused_g1(const int* __restrict__ cnt,
                                                const int* __restrict__ ell,
                                                const float* __restrict__ dinv,
                                                const u16* __restrict__ xs,
                                                const u16* __restrict__ W1t,
                                                const float* __restrict__ b1,
                                                u16* __restrict__ hb,
                                                float* __restrict__ pstats) {
    __shared__ u16 As[G1_ROWS * G1_LD];   // 17.4 KB
    int tid = threadIdx.x;
    int base = blockIdx.x * G1_ROWS;
    int q = tid & 15;

    #pragma unroll
    for (int rnd = 0; rnd < 4; ++rnd) {
        int lrow = rnd * 16 + (tid >> 4);
        int node = base + lrow;
        int cn = node < N_NODES ? node : N_NODES - 1;   // clamp; extra rows discarded later
        int len = cnt[cn];
        const int* rowp = ell + (size_t)cn * ELL_W;
        float acc[8] = {};
        int e = 0;
        for (; e + 7 < len; e += 8) {
            int4 v0 = *(const int4*)(xs + (size_t)rowp[e + 0] * F_IN + q * 8);
            int4 v1 = *(const int4*)(xs + (size_t)rowp[e + 1] * F_IN + q * 8);
            int4 v2 = *(const int4*)(xs + (size_t)rowp[e + 2] * F_IN + q * 8);
            int4 v3 = *(const int4*)(xs + (size_t)rowp[e + 3] * F_IN + q * 8);
            int4 v4 = *(const int4*)(xs + (size_t)rowp[e + 4] * F_IN + q * 8);
            int4 v5 = *(const int4*)(xs + (size_t)rowp[e + 5] * F_IN + q * 8);
            int4 v6 = *(const int4*)(xs + (size_t)rowp[e + 6] * F_IN + q * 8);
            int4 v7 = *(const int4*)(xs + (size_t)rowp[e + 7] * F_IN + q * 8);
            ACC4(v0); ACC4(v1); ACC4(v2); ACC4(v3);
            ACC4(v4); ACC4(v5); ACC4(v6); ACC4(v7);
        }
        for (; e + 1 < len; e += 2) {
            int4 v0 = *(const int4*)(xs + (size_t)rowp[e + 0] * F_IN + q * 8);
            int4 v1 = *(const int4*)(xs + (size_t)rowp[e + 1] * F_IN + q * 8);
            ACC4(v0); ACC4(v1);
        }
        if (e < len) {
            int4 v0 = *(const int4*)(xs + (size_t)rowp[e] * F_IN + q * 8);
            ACC4(v0);
        }
        float dd = dinv[cn];
        int4 o;
        o.x = (int)((u32)f2bf(acc[0] * dd) | ((u32)f2bf(acc[1] * dd) << 16));
        o.y = (int)((u32)f2bf(acc[2] * dd) | ((u32)f2bf(acc[3] * dd) << 16));
        o.z = (int)((u32)f2bf(acc[4] * dd) | ((u32)f2bf(acc[5] * dd) << 16));
        o.w = (int)((u32)f2bf(acc[6] * dd) | ((u32)f2bf(acc[7] * dd) << 16));
        *(int4*)(As + lrow * G1_LD + q * 8) = o;
    }
    __syncthreads();

    int lane = tid & 63, w = tid >> 6;
    int r = lane & 15, g = lane >> 4;

    bf16x8 wf[2][4];   // [ch-tile][kstep], resident
    #pragma unroll
    for (int t = 0; t < 2; ++t)
        #pragma unroll
        for (int ks = 0; ks < 4; ++ks)
            wf[t][ks] = *(const bf16x8*)(W1t + (w * 32 + t * 16 + r) * H_DIM + ks * 32 + g * 8);

    float bch[2][4];
    #pragma unroll
    for (int t = 0; t < 2; ++t)
        #pragma unroll
        for (int i = 0; i < 4; ++i)
            bch[t][i] = b1[w * 32 + t * 16 + 4 * g + i];

    float cs[8] = {}, cq[8] = {};

    #pragma unroll
    for (int rt = 0; rt < 4; ++rt) {
        f32x4 acc0 = {0.f, 0.f, 0.f, 0.f}, acc1 = {0.f, 0.f, 0.f, 0.f};
        #pragma unroll
        for (int ks = 0; ks < 4; ++ks) {
            bf16x8 nf = *(const bf16x8*)(As + (rt * 16 + r) * G1_LD + ks * 32 + g * 8);
            acc0 = __builtin_amdgcn_mfma_f32_16x16x32_bf16(wf[0][ks], nf, acc0, 0, 0, 0);
            acc1 = __builtin_amdgcn_mfma_f32_16x16x32_bf16(wf[1][ks], nf, acc1, 0, 0, 0);
        }
        int node = base + rt * 16 + r;
        if (node < N_NODES) {
            float o0[4], o1[4];
            #pragma unroll
            for (int i = 0; i < 4; ++i) {
                o0[i] = fmaxf(acc0[i] + bch[0][i], 0.f);
                o1[i] = fmaxf(acc1[i] + bch[1][i], 0.f);
                cs[i]     += o0[i]; cq[i]     += o0[i] * o0[i];
                cs[4 + i] += o1[i]; cq[4 + i] += o1[i] * o1[i];
            }
            uint2 p0, p1;
            p0.x = (u32)f2bf(o0[0]) | ((u32)f2bf(o0[1]) << 16);
            p0.y = (u32)f2bf(o0[2]) | ((u32)f2bf(o0[3]) << 16);
            p1.x = (u32)f2bf(o1[0]) | ((u32)f2bf(o1[1]) << 16);
            p1.y = (u32)f2bf(o1[2]) | ((u32)f2bf(o1[3]) << 16);
            u16* hp = hb + (size_t)node * H_DIM + w * 32 + 4 * g;
            *(uint2*)hp = p0;
            *(uint2*)(hp + 16) = p1;
        }
    }

    #pragma unroll
    for (int j = 0; j < 8; ++j) {
        #pragma unroll
        for (int m = 1; m < 16; m <<= 1) {
            cs[j] += __shfl_xor(cs[j], m, 16);
            cq[j] += __shfl_xor(cq[j], m, 16);
        }
    }
    if (r == 0) {
        #pragma unroll
        for (int j = 0; j < 8; ++j) {
            int c = w * 32 + (j >> 2) * 16 + 4 * g + (j & 3);
            pstats[c * PS_LD + blockIdx.x] = cs[j];
            pstats[(128 + c) * PS_LD + blockIdx.x] = cq[j];
        }
    }
}

// ---- reduce per-block partials -> scale/shift (one block per channel) ----
__global__ __launch_bounds__(256) void stats_final(const float* __restrict__ pstats,
                                                   const float* __restrict__ gamma,
                                                   const float* __restrict__ beta,
                                                   float* __restrict__ scale,
                                                   float* __restrict__ shift) {
    __shared__ float ls[256], lq[256];
    int c = blockIdx.x, t = threadIdx.x;
    float s = 0.f, q = 0.f;
    for (int b = t; b < G1_NB; b += 256) {
        s += pstats[c * PS_LD + b];
        q += pstats[(128 + c) * PS_LD + b];
    }
    ls[t] = s; lq[t] = q;
    __syncthreads();
    for (int off = 128; off; off >>= 1) {
        if (t < off) { ls[t] += ls[t + off]; lq[t] += lq[t + off]; }
        __syncthreads();
    }
    if (t == 0) {
        const float invn = 1.0f / (float)N_NODES;
        float mean = ls[0] * invn;
        float var = lq[0] * invn - mean * mean;
        float sc = gamma[c] * rsqrtf(var + BN_EPS);
        scale[c] = sc;
        shift[c] = beta[c] - mean * sc;
    }
}

// ---- fold BN into layer-2 weights; K[c] = sum_k shift[k]*W2[k][c] ----
__global__ __launch_bounds__(256) void w2fold(const float* __restrict__ W2,
                                              const float* __restrict__ scale,
                                              const float* __restrict__ shift,
                                              u16* __restrict__ W2t,
                                              float* __restrict__ K) {
    int t = threadIdx.x;
    for (int i = t; i < 48 * 128; i += 256) {
        int c = i >> 7, k = i & 127;
        W2t[i] = (c < C_OUT) ? f2bf(scale[k] * W2[k * C_OUT + c]) : (u16)0;
    }
    if (t < 48) {
        float a = 0.f;
        if (t < C_OUT)
            for (int k = 0; k < H_DIM; ++k) a += shift[k] * W2[k * C_OUT + t];
        K[t] = a;
    }
}

// ---- GEMM2 via MFMA: h2s[n] = bf16( dinv[n] * (hb[n]@W2t + K) )  (48 ch) ---
__global__ __launch_bounds__(256) void gemm2_mfma(const u16* __restrict__ hb,
                                                  const u16* __restrict__ W2t,
                                                  const float* __restrict__ K,
                                                  const float* __restrict__ dinv,
                                                  u16* __restrict__ h2s) {
    __shared__ u16 As[G2_ROWS * G1_LD];
    int tid = threadIdx.x;
    int base = blockIdx.x * G2_ROWS;

    {
        int row = tid >> 1, half = tid & 1;
        int gr = base + row; if (gr >= N_NODES) gr = N_NODES - 1;
        const int4* gsrc = (const int4*)(hb + (size_t)gr * H_DIM + half * 64);
        int4* ldst = (int4*)(As + row * G1_LD + half * 64);
        #pragma unroll
        for (int i = 0; i < 8; ++i) ldst[i] = gsrc[i];
    }
    __syncthreads();

    int lane = tid & 63, w = tid >> 6;
    int r = lane & 15, g = lane >> 4;

    bf16x8 wf[3][4];
    #pragma unroll
    for (int t = 0; t < 3; ++t)
        #pragma unroll
        for (int ks = 0; ks < 4; ++ks)
            wf[t][ks] = *(const bf16x8*)(W2t + (t * 16 + r) * H_DIM + ks * 32 + g * 8);

    float kv[3][4];
    #pragma unroll
    for (int t = 0; t < 3; ++t)
        #pragma unroll
        for (int i = 0; i < 4; ++i)
            kv[t][i] = K[t * 16 + 4 * g + i];

    f32x4 acc[2][3];
    #pragma unroll
    for (int i2 = 0; i2 < 2; ++i2)
        #pragma unroll
        for (int t = 0; t < 3; ++t)
            acc[i2][t] = (f32x4){0.f, 0.f, 0.f, 0.f};

    #pragma unroll
    for (int i2 = 0; i2 < 2; ++i2) {
        int rt = 2 * w + i2;
        #pragma unroll
        for (int ks = 0; ks < 4; ++ks) {
            bf16x8 nf = *(const bf16x8*)(As + (rt * 16 + r) * G1_LD + ks * 32 + g * 8);
            acc[i2][0] = __builtin_amdgcn_mfma_f32_16x16x32_bf16(wf[0][ks], nf, acc[i2][0], 0, 0, 0);
            acc[i2][1] = __builtin_amdgcn_mfma_f32_16x16x32_bf16(wf[1][ks], nf, acc[i2][1], 0, 0, 0);
            acc[i2][2] = __builtin_amdgcn_mfma_f32_16x16x32_bf16(wf[2][ks], nf, acc[i2][2], 0, 0, 0);
        }
    }

    #pragma unroll
    for (int i2 = 0; i2 < 2; ++i2) {
        int node = base + (2 * w + i2) * 16 + r;
        if (node < N_NODES) {
            float dd = dinv[node];
            u16* hp = h2s + (size_t)node * C_OUT + 4 * g;
            #pragma unroll
            for (int t = 0; t < 2; ++t) {
                uint2 p;
                p.x = (u32)f2bf((acc[i2][t][0] + kv[t][0]) * dd) |
                      ((u32)f2bf((acc[i2][t][1] + kv[t][1]) * dd) << 16);
                p.y = (u32)f2bf((acc[i2][t][2] + kv[t][2]) * dd) |
                      ((u32)f2bf((acc[i2][t][3] + kv[t][3]) * dd) << 16);
                *(uint2*)(hp + t * 16) = p;
            }
            if (g < 2) {
                uint2 p;
                p.x = (u32)f2bf((acc[i2][2][0] + kv[2][0]) * dd) |
                      ((u32)f2bf((acc[i2][2][1] + kv[2][1]) * dd) << 16);
                p.y = (u32)f2bf((acc[i2][2][2] + kv[2][2]) * dd) |
                      ((u32)f2bf((acc[i2][2][3] + kv[2][3]) * dd) << 16);
                *(uint2*)(hp + 32) = p;
            }
        }
    }
}

// --- gather layer 2: out[n] = logsoftmax(dinv[n]*sum h2s[s] + b2), 16 ln/node
__global__ __launch_bounds__(256) void gather2_fused(const int* __restrict__ cnt,
                                                     const int* __restrict__ ell,
                                                     const float* __restrict__ dinv,
                                                     const u16* __restrict__ h2s,
                                                     const float* __restrict__ b2,
                                                     float* __restrict__ out) {
    int node = blockIdx.x * 16 + (threadIdx.x >> 4);     // grid exact: N%16==0
    int q = threadIdx.x & 15;
    int len = cnt[node];
    const int* rowp = ell + (size_t)node * ELL_W;
    float a0 = 0.f, a1 = 0.f, a2 = 0.f, a3 = 0.f;
    int e = 0;
    for (; e + 7 < len; e += 8) {
        if (q < 10) {
            uint2 v0 = *(const uint2*)(h2s + (size_t)rowp[e + 0] * C_OUT + q * 4);
            uint2 v1 = *(const uint2*)(h2s + (size_t)rowp[e + 1] * C_OUT + q * 4);
            uint2 v2 = *(const uint2*)(h2s + (size_t)rowp[e + 2] * C_OUT + q * 4);
            uint2 v3 = *(const uint2*)(h2s + (size_t)rowp[e + 3] * C_OUT + q * 4);
            uint2 v4 = *(const uint2*)(h2s + (size_t)rowp[e + 4] * C_OUT + q * 4);
            uint2 v5 = *(const uint2*)(h2s + (size_t)rowp[e + 5] * C_OUT + q * 4);
            uint2 v6 = *(const uint2*)(h2s + (size_t)rowp[e + 6] * C_OUT + q * 4);
            uint2 v7 = *(const uint2*)(h2s + (size_t)rowp[e + 7] * C_OUT + q * 4);
            add2(&a0, &a1, v0.x); add2(&a2, &a3, v0.y);
            add2(&a0, &a1, v1.x); add2(&a2, &a3, v1.y);
            add2(&a0, &a1, v2.x); add2(&a2, &a3, v2.y);
            add2(&a0, &a1, v3.x); add2(&a2, &a3, v3.y);
            add2(&a0, &a1, v4.x); add2(&a2, &a3, v4.y);
            add2(&a0, &a1, v5.x); add2(&a2, &a3, v5.y);
            add2(&a0, &a1, v6.x); add2(&a2, &a3, v6.y);
            add2(&a0, &a1, v7.x); add2(&a2, &a3, v7.y);
        }
    }
    for (; e < len; ++e) {
        int s = rowp[e];
        if (q < 10) {
            uint2 v = *(const uint2*)(h2s + (size_t)s * C_OUT + q * 4);
            add2(&a0, &a1, v.x); add2(&a2, &a3, v.y);
        }
    }
    float dd = dinv[node];
    float4 r;
    float m = -INFINITY;
    if (q < 10) {
        float4 bv = *(const float4*)(b2 + q * 4);
        r.x = fmaf(a0, dd, bv.x); r.y = fmaf(a1, dd, bv.y);
        r.z = fmaf(a2, dd, bv.z); r.w = fmaf(a3, dd, bv.w);
        m = fmaxf(fmaxf(r.x, r.y), fmaxf(r.z, r.w));
    }
    #pragma unroll
    for (int off = 1; off < 16; off <<= 1) m = fmaxf(m, __shfl_xor(m, off, 16));
    float ex = 0.f;
    if (q < 10)
        ex = expf(r.x - m) + expf(r.y - m) + expf(r.z - m) + expf(r.w - m);
    #pragma unroll
    for (int off = 1; off < 16; off <<= 1) ex += __shfl_xor(ex, off, 16);
    float lse = logf(ex) + m;
    if (q < 10) {
        float4 o = {r.x - lse, r.y - lse, r.z - lse, r.w - lse};
        *(float4*)(out + (size_t)node * C_OUT + q * 4) = o;
    }
}

// ---------------- launch ----------------
extern "C" void kernel_launch(void* const* d_in, const int* in_sizes, int n_in,
                              void* d_out, int out_size, void* d_ws, size_t ws_size,
                              hipStream_t stream) {
    const float* x     = (const float*)d_in[0];
    const int*   eidx  = (const int*)d_in[1];
    const float* W1    = (const float*)d_in[2];
    const float* b1    = (const float*)d_in[3];
    const float* gamma = (const float*)d_in[4];
    const float* beta  = (const float*)d_in[5];
    const float* W2    = (const float*)d_in[6];
    const float* b2    = (const float*)d_in[7];
    float* out = (float*)d_out;

    const int* src = eidx;
    const int* dst = eidx + N_EDGES;

    // workspace layout (dword units)
    float* ws = (float*)d_ws;
    float* dinv    = ws;                        // N
    int*   cnt     = (int*)(ws + 100000);       // N
    int*   bcur    = (int*)(ws + 200000);       // NBKT*16 (+pad)
    int*   ell     = (int*)(ws + 203200);       // N*64 = 6.4M
    u16*   xs      = (u16*)(ws + 6603200);      // N*128 bf16 (6.4M dwords)
    u16*   h2s     = (u16*)(ws + 6603200);      // aliases xs (xs dead after fused_g1)
    u16*   hb      = (u16*)(ws + 13003200);     // N*128 bf16 (6.4M dwords)
    int2*  region  = (int2*)(ws + 13003200);    // aliases hb (region dead before fused_g1)
    u16*   W1t     = (u16*)(ws + 19403200);     // 128*128 bf16 = 8192 dwords
    float* pstats  = ws + 19411392;             // 256*1600 f32 = 409600
    float* scale   = ws + 19820992;             // 128
    float* shift   = ws + 19821120;             // 128
    float* K       = ws + 19821248;             // 48 (+pad)
    u16*   W2t     = (u16*)(ws + 19821312);     // 48*128 bf16 = 3072 dwords

    size_t needed = (size_t)(19821312 + 3072 + 256) * 4;   // ~79.3 MB
    if (ws_size < needed) return;

    // graph build: bucket scatter + per-bucket ELL build (no global scans)
    hipMemsetAsync(bcur, 0, NBKT * CNT_STRIDE * 4, stream);
    bucket_scatter<<<P_NB, 256, 0, stream>>>(src, dst, bcur, region);
    ell_build<<<NBKT, 256, 0, stream>>>(bcur, region, ell, cnt, dinv);

    // layer 1 (gather fused into GEMM1)
    xconvert<<<N_NODES * F_IN / 4 / 256, 256, 0, stream>>>(x, dinv, xs);
    wconvert<<<F_IN * H_DIM / 256, 256, 0, stream>>>(W1, W1t);
    fused_g1<<<G1_NB, 256, 0, stream>>>(cnt, ell, dinv, xs, W1t, b1, hb, pstats);
    stats_final<<<128, 256, 0, stream>>>(pstats, gamma, beta, scale, shift);
    w2fold<<<1, 256, 0, stream>>>(W2, scale, shift, W2t, K);

    // layer 2
    gemm2_mfma<<<G2_NB, 256, 0, stream>>>(hb, W2t, K, dinv, h2s);
    gather2_fused<<<N_NODES / 16, 256, 0, stream>>>(cnt, ell, dinv, h2s, b2, out);
}